// Round 6
// baseline (19062.022 us; speedup 1.0000x reference)
//
#include <hip/hip_runtime.h>

#define B_ 512
#define N_ 256
#define D_ 256
#define NEGINF (-1e30)

typedef float v4f __attribute__((ext_vector_type(4)));

// ---- packW: w (768x256 row-major) -> wave-packed v4f layout -------------------
// dst[((w16*16 + k)*3 + g)*64 + l], w16=o>>4, k=c4&15, l=4*(o&15)+(c4>>4), j=g*256+o
__global__ __launch_bounds__(256) void packW_k(const float* __restrict__ in,
                                               float* __restrict__ out) {
  int idx = blockIdx.x * 256 + threadIdx.x;  // 49152 v4f
  int j = idx >> 6, c4 = idx & 63;
  int g = j >> 8, o = j & 255;
  int w16 = o >> 4, k = c4 & 15, l = 4 * (o & 15) + (c4 >> 4);
  ((v4f*)out)[((w16 * 16 + k) * 3 + g) * 64 + l] = ((const v4f*)in)[idx];
}

// ---- Wqk[c][e] = sum_d wk[d][c]*wq[d][e] (fp64), packed; bqk[c]=sum wk[d][c]*bq[d]
__global__ __launch_bounds__(256) void wqk_k(const float* __restrict__ wk,
                                             const float* __restrict__ wq,
                                             const float* __restrict__ bq,
                                             double* __restrict__ WqkP,
                                             double* __restrict__ bqk) {
  int c = blockIdx.x, e = threadIdx.x;
  double acc = 0.0;
  for (int dd = 0; dd < 256; ++dd)
    acc += (double)wk[dd * 256 + c] * (double)wq[dd * 256 + e];
  int w16 = c >> 4, k2 = (e >> 1) & 31, l = 4 * (c & 15) + (e >> 6), comp = e & 1;
  WqkP[(size_t)(((w16 * 32) + k2) * 64 + l) * 2 + comp] = acc;
  if (e == 0) {
    double s = 0.0;
    for (int dd = 0; dd < 256; ++dd) s += (double)wk[dd * 256 + c] * (double)bq[dd];
    bqk[c] = s;
  }
}

// ---- encP: wave-packed per-row layout: eP4[b][(w16*16+k)*64+l] ----------------
// n = w16*16 + (l>>2), c4 = (l&3)*16 + k
__global__ __launch_bounds__(256) void encp_k(const float* __restrict__ enc,
                                              float* __restrict__ encP) {
  int b = blockIdx.y;
  int idx = blockIdx.x * 256 + threadIdx.x;  // 16384 v4f per b
  int l = idx & 63, rest = idx >> 6;
  int k = rest & 15, w16 = rest >> 4;
  int n = w16 * 16 + (l >> 2), c4 = (l & 3) * 16 + k;
  ((v4f*)encP)[(size_t)b * 16384 + idx] =
      *(const v4f*)(enc + (size_t)b * 65536 + n * 256 + c4 * 4);
}

// ---------------- persistent decode: 2 rows/block, 1024 thr, 4 barriers/step --
__global__ __launch_bounds__(1024, 4) void decode_k(
    const float* __restrict__ enc, const float* __restrict__ init_token,
    const float* __restrict__ b_ih, const float* __restrict__ b_hh,
    const float* __restrict__ wihP, const float* __restrict__ whhP,
    const double* __restrict__ WqkP, const double* __restrict__ bqk,
    const float* __restrict__ encP, float* __restrict__ out) {
  const int tid = threadIdx.x;
  const int WV = tid >> 6;            // wave 0..15
  const int LN = tid & 63;            // lane
  const int O = WV * 16 + (LN >> 2);  // output index 0..255
  const int S = LN & 3;               // slice 0..3  (c-range [64S, 64S+64))
  const int ROW = S >> 1;             // row this lane finalizes
  const int b0 = blockIdx.x * 2;
  const int OP = O + ((O >> 6) << 1);  // padded index of O
  const int CB = S * 66;               // padded base of slice S

  // pad 2 doubles per 64 -> slice bases on banks {0,4,8,12}, 16B-aligned groups
  __shared__ alignas(16) double hS[2][2][264];  // [pingpong][row][pad(d)]
  __shared__ alignas(16) double xS[2][264];
  __shared__ alignas(16) double qs[2][264];
  __shared__ double lg[2][N_];
  __shared__ unsigned char maskS[2][N_];
  __shared__ double redA[16][2], redB[16][2], redC[16][2];
  __shared__ int redI[16][2];

  const float* encB0 = enc + (size_t)b0 * 65536;
  const float* encB1 = encB0 + 65536;
  const v4f* eP0 = (const v4f*)encP + (size_t)b0 * 16384;
  const v4f* eP1 = eP0 + 16384;
  const v4f* wh4 = (const v4f*)whhP;
  const v4f* wi4 = (const v4f*)wihP;
  const double2* Wp2 = (const double2*)WqkP;

  // ---------------- init ----------------
  if (tid < 256) {
    double iv = (double)init_token[tid];
    int p = tid + ((tid >> 6) << 1);
    xS[0][p] = iv;
    xS[1][p] = iv;
    maskS[0][tid] = 1;
    maskS[1][tid] = 1;
  }
  {
    double p0 = 0.0, p1 = 0.0;
    const float* e0 = encB0 + (size_t)(S * 64) * 256 + O;
    const float* e1 = encB1 + (size_t)(S * 64) * 256 + O;
#pragma unroll 4
    for (int n = 0; n < 64; ++n) { p0 += (double)e0[n * 256]; p1 += (double)e1[n * 256]; }
    p0 += __shfl_xor(p0, 1); p0 += __shfl_xor(p0, 2);
    p1 += __shfl_xor(p1, 1); p1 += __shfl_xor(p1, 2);
    if (S == 0) {
      hS[0][0][OP] = p0 * (1.0 / 256.0);
      hS[0][1][OP] = p1 * (1.0 / 256.0);
    }
  }
  __syncthreads();

  int cur = 0;
  for (int t = 0; t < N_; ++t) {
    const int nxt = cur ^ 1;
    // ---- P1: GRU (h-side + x-side), split-K over S, xor-combine ----
    double ghr0 = 0, ghz0 = 0, ghn0 = 0, ghr1 = 0, ghz1 = 0, ghn1 = 0;
    double air0 = 0, aiz0 = 0, ain0 = 0, air1 = 0, aiz1 = 0, ain1 = 0;
#pragma unroll 4
    for (int k = 0; k < 16; ++k) {
      int wb = ((WV * 16 + k) * 3) * 64 + LN;
      v4f br = wh4[wb], bz = wh4[wb + 64], bn = wh4[wb + 128];
      v4f ar = wi4[wb], az = wi4[wb + 64], an = wi4[wb + 128];
      const double* h0 = &hS[cur][0][CB + 4 * k];
      const double* h1 = &hS[cur][1][CB + 4 * k];
      const double* x0 = &xS[0][CB + 4 * k];
      const double* x1 = &xS[1][CB + 4 * k];
#pragma unroll
      for (int i = 0; i < 4; ++i) {
        double wr = (double)br[i], wz = (double)bz[i], wn = (double)bn[i];
        ghr0 += wr * h0[i]; ghz0 += wz * h0[i]; ghn0 += wn * h0[i];
        ghr1 += wr * h1[i]; ghz1 += wz * h1[i]; ghn1 += wn * h1[i];
        double vr = (double)ar[i], vz = (double)az[i], vn = (double)an[i];
        air0 += vr * x0[i]; aiz0 += vz * x0[i]; ain0 += vn * x0[i];
        air1 += vr * x1[i]; aiz1 += vz * x1[i]; ain1 += vn * x1[i];
      }
    }
    ghr0 += __shfl_xor(ghr0, 1); ghr0 += __shfl_xor(ghr0, 2);
    ghz0 += __shfl_xor(ghz0, 1); ghz0 += __shfl_xor(ghz0, 2);
    ghn0 += __shfl_xor(ghn0, 1); ghn0 += __shfl_xor(ghn0, 2);
    ghr1 += __shfl_xor(ghr1, 1); ghr1 += __shfl_xor(ghr1, 2);
    ghz1 += __shfl_xor(ghz1, 1); ghz1 += __shfl_xor(ghz1, 2);
    ghn1 += __shfl_xor(ghn1, 1); ghn1 += __shfl_xor(ghn1, 2);
    air0 += __shfl_xor(air0, 1); air0 += __shfl_xor(air0, 2);
    aiz0 += __shfl_xor(aiz0, 1); aiz0 += __shfl_xor(aiz0, 2);
    ain0 += __shfl_xor(ain0, 1); ain0 += __shfl_xor(ain0, 2);
    air1 += __shfl_xor(air1, 1); air1 += __shfl_xor(air1, 2);
    aiz1 += __shfl_xor(aiz1, 1); aiz1 += __shfl_xor(aiz1, 2);
    ain1 += __shfl_xor(ain1, 1); ain1 += __shfl_xor(ain1, 2);
    {
      double gir = (ROW ? air1 : air0) + (double)b_ih[O];
      double giz = (ROW ? aiz1 : aiz0) + (double)b_ih[256 + O];
      double gin = (ROW ? ain1 : ain0) + (double)b_ih[512 + O];
      double hr_ = (ROW ? ghr1 : ghr0) + (double)b_hh[O];
      double hz_ = (ROW ? ghz1 : ghz0) + (double)b_hh[256 + O];
      double hn_ = (ROW ? ghn1 : ghn0) + (double)b_hh[512 + O];
      double rr = 1.0 / (1.0 + exp(-(gir + hr_)));
      double zz = 1.0 / (1.0 + exp(-(giz + hz_)));
      double nn = tanh(gin + rr * hn_);
      double hold = hS[cur][ROW][OP];
      double hnew = (1.0 - zz) * nn + zz * hold;
      if ((S & 1) == 0) hS[nxt][ROW][OP] = hnew;
    }
    __syncthreads();  // B1: h ready

    // ---- P2: qk = Wqk·h + bqk ----
    {
      double q0 = 0, q1 = 0;
#pragma unroll 8
      for (int k = 0; k < 32; ++k) {
        double2 wv = Wp2[(WV * 32 + k) * 64 + LN];
        const double* h0 = &hS[nxt][0][CB + 2 * k];
        const double* h1 = &hS[nxt][1][CB + 2 * k];
        q0 += wv.x * h0[0] + wv.y * h0[1];
        q1 += wv.x * h1[0] + wv.y * h1[1];
      }
      q0 += __shfl_xor(q0, 1); q0 += __shfl_xor(q0, 2);
      q1 += __shfl_xor(q1, 1); q1 += __shfl_xor(q1, 2);
      if (S == 0) {
        double bb = bqk[O];
        qs[0][OP] = q0 + bb;
        qs[1][OP] = q1 + bb;
      }
    }
    __syncthreads();  // B2: qs ready

    // ---- P3: logits + wave argmax + wave-local exp sums ----
    {
      double p0 = 0, p1 = 0;
#pragma unroll 8
      for (int k = 0; k < 16; ++k) {
        int eb = (WV * 16 + k) * 64 + LN;
        v4f e0 = eP0[eb];
        v4f e1 = eP1[eb];
        const double* qa = &qs[0][CB + 4 * k];
        const double* qb = &qs[1][CB + 4 * k];
#pragma unroll
        for (int i = 0; i < 4; ++i) {
          p0 += (double)e0[i] * qa[i];
          p1 += (double)e1[i] * qb[i];
        }
      }
      p0 += __shfl_xor(p0, 1); p0 += __shfl_xor(p0, 2);
      p1 += __shfl_xor(p1, 1); p1 += __shfl_xor(p1, 2);
      double lgv0 = 0.0625 * p0; if (!maskS[0][O]) lgv0 = NEGINF;
      double lgv1 = 0.0625 * p1; if (!maskS[1][O]) lgv1 = NEGINF;
      if (S == 0) { lg[0][O] = lgv0; lg[1][O] = lgv1; }
      double v0 = lgv0, v1 = lgv1;
      int i0 = O, i1 = O;
#pragma unroll
      for (int off = 1; off < 64; off <<= 1) {
        double t0 = __shfl_xor(v0, off); int ti0 = __shfl_xor(i0, off);
        if (t0 > v0 || (t0 == v0 && ti0 < i0)) { v0 = t0; i0 = ti0; }
        double t1 = __shfl_xor(v1, off); int ti1 = __shfl_xor(i1, off);
        if (t1 > v1 || (t1 == v1 && ti1 < i1)) { v1 = t1; i1 = ti1; }
      }
      // wave-local exp sums relative to wave max (S==0 lanes contribute)
      double e0 = (S == 0) ? exp(lgv0 - v0) : 0.0;
      double e1 = (S == 0) ? exp(lgv1 - v1) : 0.0;
      double s20 = e0 * (lgv0 - v0);
      double s21 = e1 * (lgv1 - v1);
#pragma unroll
      for (int off = 1; off < 64; off <<= 1) {
        e0 += __shfl_xor(e0, off);
        s20 += __shfl_xor(s20, off);
        e1 += __shfl_xor(e1, off);
        s21 += __shfl_xor(s21, off);
      }
      if (LN == 0) {
        redA[WV][0] = v0; redI[WV][0] = i0; redB[WV][0] = e0; redC[WV][0] = s20;
        redA[WV][1] = v1; redI[WV][1] = i1; redB[WV][1] = e1; redC[WV][1] = s21;
      }
    }
    __syncthreads();  // B3: per-wave stats ready

    // ---- P4: wave-0 global combine + outputs; all gatherers fetch next x ----
    if (tid < 32) {
      int r = LN >> 4, w = LN & 15;
      double mw = redA[w][r];
      int iw = redI[w][r];
      double s1w = redB[w][r], s2w = redC[w][r];
      double m = mw;
      int am = iw;
#pragma unroll
      for (int off = 1; off < 16; off <<= 1) {
        double om = __shfl_xor(m, off); int oi = __shfl_xor(am, off);
        if (om > m || (om == m && oi < am)) { m = om; am = oi; }
      }
      double sc = exp(mw - m);  // 0 for fully-masked waves -> kills junk terms
      double S1 = s1w * sc;
      double S2 = (s2w + (mw - m) * s1w) * sc;
#pragma unroll
      for (int off = 1; off < 16; off <<= 1) {
        S1 += __shfl_xor(S1, off);
        S2 += __shfl_xor(S2, off);
      }
      if (w == 0) {
        double lS = log(S1);
        double logZ = m + lS;
        size_t row = (size_t)(b0 + r) * N_;
        out[row + t] = (float)am;
        out[(size_t)B_ * N_ + row + t] = (float)(lg[r][am] - logZ);
        out[2 * (size_t)B_ * N_ + row + t] = (float)(lS - S2 / S1);
        maskS[r][am] = 0;
      }
    }
    if (tid < 512) {
      int r = tid >> 8, j = tid & 255;
      double bv = redA[0][r];
      int am = redI[0][r];
#pragma unroll 4
      for (int w = 1; w < 16; ++w) {
        double wv = redA[w][r]; int wi = redI[w][r];
        if (wv > bv || (wv == bv && wi < am)) { bv = wv; am = wi; }
      }
      int c4 = j >> 2;
      int vidx = ((am >> 4) * 16 + (c4 & 15)) * 64 + (4 * (am & 15) + (c4 >> 4));
      const float* ePr = r ? (const float*)eP1 : (const float*)eP0;
      xS[r][j + ((j >> 6) << 1)] = (double)ePr[vidx * 4 + (j & 3)];
    }
    __syncthreads();  // B4: x, mask, outputs done
    cur ^= 1;
  }
}

extern "C" void kernel_launch(void* const* d_in, const int* in_sizes, int n_in,
                              void* d_out, int out_size, void* d_ws, size_t ws_size,
                              hipStream_t stream) {
  const float* enc = (const float*)d_in[0];
  const float* init_token = (const float*)d_in[1];
  const float* w_ih = (const float*)d_in[2];
  const float* w_hh = (const float*)d_in[3];
  const float* b_ih = (const float*)d_in[4];
  const float* b_hh = (const float*)d_in[5];
  const float* wq = (const float*)d_in[6];
  const float* bq = (const float*)d_in[7];
  const float* wk = (const float*)d_in[8];
  const float* bk = (const float*)d_in[9];  // folded out by softmax shift-invariance
  (void)bk;
  float* out = (float*)d_out;
  char* wsb = (char*)d_ws;

  // ws layout (bytes)
  float* wihP = (float*)(wsb + 0);          //    786,432
  float* whhP = (float*)(wsb + 786432);     //    786,432
  double* WqkP = (double*)(wsb + 1572864);  //    524,288
  double* bqk = (double*)(wsb + 2097152);   //      2,048
  float* encP = (float*)(wsb + 2099200);    // 134,217,728  (end: 136,316,928)

  hipLaunchKernelGGL(packW_k, dim3(192), dim3(256), 0, stream, w_ih, wihP);
  hipLaunchKernelGGL(packW_k, dim3(192), dim3(256), 0, stream, w_hh, whhP);
  hipLaunchKernelGGL(wqk_k, dim3(256), dim3(256), 0, stream, wk, wq, bq, WqkP, bqk);
  hipLaunchKernelGGL(encp_k, dim3(64, 512), dim3(256), 0, stream, enc, encP);
  hipLaunchKernelGGL(decode_k, dim3(B_ / 2), dim3(1024), 0, stream, enc, init_token,
                     b_ih, b_hh, wihP, whhP, WqkP, bqk, encP, out);
}

// Round 7
// 18722.784 us; speedup vs baseline: 1.0181x; 1.0181x over previous
//
#include <hip/hip_runtime.h>

#define B_ 512
#define N_ 256
#define D_ 256
#define NEGINF (-1e30)

typedef float v4f __attribute__((ext_vector_type(4)));

__device__ __forceinline__ v4f ntload4(const v4f* p) {
  return __builtin_nontemporal_load(p);
}
__device__ __forceinline__ double ntload8(const double* p) {
  return __builtin_nontemporal_load(p);
}

// ---------------- transpose: out[c][r] = in[r][c], in is R x C ----------------
__global__ void transpose_k(const float* __restrict__ in, float* __restrict__ out,
                            int R, int C) {
  __shared__ float tile[32][33];
  int rb = blockIdx.y * 32, cb = blockIdx.x * 32;
  int tx = threadIdx.x, ty = threadIdx.y;  // block (32,8)
  for (int i = ty; i < 32; i += 8) {
    int r = rb + i, c = cb + tx;
    if (r < R && c < C) tile[i][tx] = in[r * C + c];
  }
  __syncthreads();
  for (int i = ty; i < 32; i += 8) {
    int c = cb + i, r = rb + tx;
    if (r < R && c < C) out[c * R + r] = tile[tx][i];
  }
}

// ---- packW: w (768x256 row-major) -> wave-packed v4f layout -------------------
__global__ __launch_bounds__(256) void packW_k(const float* __restrict__ in,
                                               float* __restrict__ out) {
  int idx = blockIdx.x * 256 + threadIdx.x;  // 49152 v4f
  int j = idx >> 6, c4 = idx & 63;
  int g = j >> 8, o = j & 255;
  int w16 = o >> 4, k = c4 & 15, l = 4 * (o & 15) + (c4 >> 4);
  ((v4f*)out)[((w16 * 16 + k) * 3 + g) * 64 + l] = ((const v4f*)in)[idx];
}

// ---- Wqk packed fp64; bqk[c] = sum_d wk[d][c]*bq[d] ---------------------------
__global__ __launch_bounds__(256) void wqk_k(const float* __restrict__ wk,
                                             const float* __restrict__ wq,
                                             const float* __restrict__ bq,
                                             double* __restrict__ WqkP,
                                             double* __restrict__ bqk) {
  int c = blockIdx.x, e = threadIdx.x;
  double acc = 0.0;
  for (int dd = 0; dd < 256; ++dd)
    acc += (double)wk[dd * 256 + c] * (double)wq[dd * 256 + e];
  int w16 = c >> 4, k2 = (e >> 1) & 31, l = 4 * (c & 15) + (e >> 6), comp = e & 1;
  WqkP[(size_t)(((w16 * 32) + k2) * 64 + l) * 2 + comp] = acc;
  if (e == 0) {
    double s = 0.0;
    for (int dd = 0; dd < 256; ++dd) s += (double)wk[dd * 256 + c] * (double)bq[dd];
    bqk[c] = s;
  }
}

// ---- encP: wave-packed per-row layout ----------------------------------------
__global__ __launch_bounds__(256) void encp_k(const float* __restrict__ enc,
                                              float* __restrict__ encP) {
  int b = blockIdx.y;
  int idx = blockIdx.x * 256 + threadIdx.x;  // 16384 v4f per b
  int l = idx & 63, rest = idx >> 6;
  int k = rest & 15, w16 = rest >> 4;
  int n = w16 * 16 + (l >> 2), c4 = (l & 3) * 16 + k;
  ((v4f*)encP)[(size_t)b * 16384 + idx] =
      *(const v4f*)(enc + (size_t)b * 65536 + n * 256 + c4 * 4);
}

// ---- Gi[(b*256+n)*768 + j] = b_ih[j] + sum_c w_ih[j][c]*enc[b][n][c]  (fp64) --
__global__ __launch_bounds__(768) void gi_k(const float* __restrict__ enc,
                                            const float* __restrict__ wihT,
                                            const float* __restrict__ b_ih,
                                            double* __restrict__ Gi) {
  int b = blockIdx.x, j = threadIdx.x;
  __shared__ float encS[32][256];
  const float* encB = enc + (size_t)b * 65536;
  double bias = (double)b_ih[j];
  for (int n0 = 0; n0 < 256; n0 += 32) {
    __syncthreads();
    for (int i = j; i < 2048; i += 768)
      ((float4*)encS)[i] = ((const float4*)(encB + n0 * 256))[i];
    __syncthreads();
    double acc[32];
#pragma unroll
    for (int jj = 0; jj < 32; ++jj) acc[jj] = bias;
    for (int c0 = 0; c0 < 256; c0 += 4) {
      double w0 = (double)wihT[(c0 + 0) * 768 + j];
      double w1 = (double)wihT[(c0 + 1) * 768 + j];
      double w2 = (double)wihT[(c0 + 2) * 768 + j];
      double w3 = (double)wihT[(c0 + 3) * 768 + j];
#pragma unroll
      for (int jj = 0; jj < 32; ++jj) {
        const float4 e = *(const float4*)&encS[jj][c0];
        acc[jj] += w0 * (double)e.x + w1 * (double)e.y + w2 * (double)e.z + w3 * (double)e.w;
      }
    }
#pragma unroll
    for (int jj = 0; jj < 32; ++jj)
      Gi[((size_t)b * 256 + n0 + jj) * 768 + j] = acc[jj];
  }
}

// ---- gi0[j] = b_ih[j] + sum_c w_ih[j][c]*init_token[c]  (fp64, one block) ----
__global__ __launch_bounds__(768) void gi0_k(const float* __restrict__ w_ih,
                                             const float* __restrict__ b_ih,
                                             const float* __restrict__ init_token,
                                             double* __restrict__ gi0) {
  int j = threadIdx.x;
  __shared__ float xs[256];
  if (j < 256) xs[j] = init_token[j];
  __syncthreads();
  double acc = (double)b_ih[j];
  for (int c = 0; c < 256; ++c) acc += (double)w_ih[j * 256 + c] * (double)xs[c];
  gi0[j] = acc;
}

// ---------------- persistent decode: 2 rows/block, 1024 thr, 4 barriers/step --
template <bool USE_GI>
__global__ __launch_bounds__(1024, 2) void decode_k(
    const float* __restrict__ enc, const float* __restrict__ init_token,
    const float* __restrict__ b_ih, const float* __restrict__ b_hh,
    const float* __restrict__ wihP, const float* __restrict__ whhP,
    const double* __restrict__ WqkP, const double* __restrict__ bqk,
    const float* __restrict__ encP, const double* __restrict__ gi0,
    const double* __restrict__ Gi, float* __restrict__ out) {
  const int tid = threadIdx.x;
  const int WV = tid >> 6;            // wave 0..15
  const int LN = tid & 63;            // lane
  const int O = WV * 16 + (LN >> 2);  // output index 0..255
  const int S = LN & 3;               // slice 0..3  (c-range [64S, 64S+64))
  const int ROW = S >> 1;             // row this lane finalizes
  const int b0 = blockIdx.x * 2;
  const int OP = O + ((O >> 6) << 1);  // padded index of O
  const int CB = S * 66;               // padded base of slice S

  // pad 2 doubles per 64 -> slice bases on banks {0,4,8,12}, 16B-aligned groups
  __shared__ alignas(16) double hS[2][2][264];  // [pingpong][row][pad(d)]
  __shared__ alignas(16) double xS[2][264];     // Tier-B only
  __shared__ alignas(16) double qs[2][264];
  __shared__ double lg[2][N_];
  __shared__ unsigned char maskS[2][N_];
  __shared__ double redA[16][2], redB[16][2], redC[16][2];
  __shared__ int redI[16][2];

  const float* encB0 = enc + (size_t)b0 * 65536;
  const float* encB1 = encB0 + 65536;
  const v4f* eP0 = (const v4f*)encP + (size_t)b0 * 16384;
  const v4f* eP1 = eP0 + 16384;
  const v4f* wh4 = (const v4f*)whhP;
  const v4f* wi4 = (const v4f*)wihP;
  const double2* Wp2 = (const double2*)WqkP;

  double giR[3];  // Tier-A: this thread's (r,z,n) input-gate values for ROW/O

  // ---------------- init ----------------
  if (tid < 256) {
    maskS[0][tid] = 1;
    maskS[1][tid] = 1;
    if (!USE_GI) {
      double iv = (double)init_token[tid];
      int p = tid + ((tid >> 6) << 1);
      xS[0][p] = iv;
      xS[1][p] = iv;
    }
  }
  if (USE_GI) {
#pragma unroll
    for (int g = 0; g < 3; ++g) giR[g] = gi0[g * 256 + O];
  }
  {
    double p0 = 0.0, p1 = 0.0;
    const float* e0 = encB0 + (size_t)(S * 64) * 256 + O;
    const float* e1 = encB1 + (size_t)(S * 64) * 256 + O;
#pragma unroll 4
    for (int n = 0; n < 64; ++n) { p0 += (double)e0[n * 256]; p1 += (double)e1[n * 256]; }
    p0 += __shfl_xor(p0, 1); p0 += __shfl_xor(p0, 2);
    p1 += __shfl_xor(p1, 1); p1 += __shfl_xor(p1, 2);
    if (S == 0) {
      hS[0][0][OP] = p0 * (1.0 / 256.0);
      hS[0][1][OP] = p1 * (1.0 / 256.0);
    }
  }
  __syncthreads();

  int cur = 0;
  for (int t = 0; t < N_; ++t) {
    const int nxt = cur ^ 1;
    // ---- P1: GRU h-side (+ x-side if Tier-B), split-K over S, xor-combine ----
    double ghr0 = 0, ghz0 = 0, ghn0 = 0, ghr1 = 0, ghz1 = 0, ghn1 = 0;
    double air0 = 0, aiz0 = 0, ain0 = 0, air1 = 0, aiz1 = 0, ain1 = 0;
#pragma unroll 8
    for (int k = 0; k < 16; ++k) {
      int wb = ((WV * 16 + k) * 3) * 64 + LN;
      v4f br = wh4[wb], bz = wh4[wb + 64], bn = wh4[wb + 128];
      const double* h0 = &hS[cur][0][CB + 4 * k];
      const double* h1 = &hS[cur][1][CB + 4 * k];
#pragma unroll
      for (int i = 0; i < 4; ++i) {
        double wr = (double)br[i], wz = (double)bz[i], wn = (double)bn[i];
        ghr0 += wr * h0[i]; ghz0 += wz * h0[i]; ghn0 += wn * h0[i];
        ghr1 += wr * h1[i]; ghz1 += wz * h1[i]; ghn1 += wn * h1[i];
      }
      if (!USE_GI) {
        v4f ar = wi4[wb], az = wi4[wb + 64], an = wi4[wb + 128];
        const double* x0 = &xS[0][CB + 4 * k];
        const double* x1 = &xS[1][CB + 4 * k];
#pragma unroll
        for (int i = 0; i < 4; ++i) {
          double vr = (double)ar[i], vz = (double)az[i], vn = (double)an[i];
          air0 += vr * x0[i]; aiz0 += vz * x0[i]; ain0 += vn * x0[i];
          air1 += vr * x1[i]; aiz1 += vz * x1[i]; ain1 += vn * x1[i];
        }
      }
    }
    ghr0 += __shfl_xor(ghr0, 1); ghr0 += __shfl_xor(ghr0, 2);
    ghz0 += __shfl_xor(ghz0, 1); ghz0 += __shfl_xor(ghz0, 2);
    ghn0 += __shfl_xor(ghn0, 1); ghn0 += __shfl_xor(ghn0, 2);
    ghr1 += __shfl_xor(ghr1, 1); ghr1 += __shfl_xor(ghr1, 2);
    ghz1 += __shfl_xor(ghz1, 1); ghz1 += __shfl_xor(ghz1, 2);
    ghn1 += __shfl_xor(ghn1, 1); ghn1 += __shfl_xor(ghn1, 2);
    if (!USE_GI) {
      air0 += __shfl_xor(air0, 1); air0 += __shfl_xor(air0, 2);
      aiz0 += __shfl_xor(aiz0, 1); aiz0 += __shfl_xor(aiz0, 2);
      ain0 += __shfl_xor(ain0, 1); ain0 += __shfl_xor(ain0, 2);
      air1 += __shfl_xor(air1, 1); air1 += __shfl_xor(air1, 2);
      aiz1 += __shfl_xor(aiz1, 1); aiz1 += __shfl_xor(aiz1, 2);
      ain1 += __shfl_xor(ain1, 1); ain1 += __shfl_xor(ain1, 2);
    }
    {
      double gir, giz, gin;
      if (USE_GI) {
        gir = giR[0]; giz = giR[1]; gin = giR[2];  // bias already folded in
      } else {
        gir = (ROW ? air1 : air0) + (double)b_ih[O];
        giz = (ROW ? aiz1 : aiz0) + (double)b_ih[256 + O];
        gin = (ROW ? ain1 : ain0) + (double)b_ih[512 + O];
      }
      double hr_ = (ROW ? ghr1 : ghr0) + (double)b_hh[O];
      double hz_ = (ROW ? ghz1 : ghz0) + (double)b_hh[256 + O];
      double hn_ = (ROW ? ghn1 : ghn0) + (double)b_hh[512 + O];
      double rr = 1.0 / (1.0 + exp(-(gir + hr_)));
      double zz = 1.0 / (1.0 + exp(-(giz + hz_)));
      double nn = tanh(gin + rr * hn_);
      double hold = hS[cur][ROW][OP];
      double hnew = (1.0 - zz) * nn + zz * hold;
      if ((S & 1) == 0) hS[nxt][ROW][OP] = hnew;
    }
    __syncthreads();  // B1: h ready

    // ---- P2: qk = Wqk·h + bqk ----
    {
      double q0 = 0, q1 = 0;
#pragma unroll 8
      for (int k = 0; k < 32; ++k) {
        double2 wv = Wp2[(WV * 32 + k) * 64 + LN];
        const double* h0 = &hS[nxt][0][CB + 2 * k];
        const double* h1 = &hS[nxt][1][CB + 2 * k];
        q0 += wv.x * h0[0] + wv.y * h0[1];
        q1 += wv.x * h1[0] + wv.y * h1[1];
      }
      q0 += __shfl_xor(q0, 1); q0 += __shfl_xor(q0, 2);
      q1 += __shfl_xor(q1, 1); q1 += __shfl_xor(q1, 2);
      if (S == 0) {
        double bb = bqk[O];
        qs[0][OP] = q0 + bb;
        qs[1][OP] = q1 + bb;
      }
    }
    __syncthreads();  // B2: qs ready

    // ---- P3: logits + wave argmax + wave-local exp sums ----
    {
      double p0 = 0, p1 = 0;
#pragma unroll 8
      for (int k = 0; k < 16; ++k) {
        int eb = (WV * 16 + k) * 64 + LN;
        v4f e0 = ntload4(eP0 + eb);
        v4f e1 = ntload4(eP1 + eb);
        const double* qa = &qs[0][CB + 4 * k];
        const double* qb = &qs[1][CB + 4 * k];
#pragma unroll
        for (int i = 0; i < 4; ++i) {
          p0 += (double)e0[i] * qa[i];
          p1 += (double)e1[i] * qb[i];
        }
      }
      p0 += __shfl_xor(p0, 1); p0 += __shfl_xor(p0, 2);
      p1 += __shfl_xor(p1, 1); p1 += __shfl_xor(p1, 2);
      double lgv0 = 0.0625 * p0; if (!maskS[0][O]) lgv0 = NEGINF;
      double lgv1 = 0.0625 * p1; if (!maskS[1][O]) lgv1 = NEGINF;
      if (S == 0) { lg[0][O] = lgv0; lg[1][O] = lgv1; }
      double v0 = lgv0, v1 = lgv1;
      int i0 = O, i1 = O;
#pragma unroll
      for (int off = 1; off < 64; off <<= 1) {
        double t0 = __shfl_xor(v0, off); int ti0 = __shfl_xor(i0, off);
        if (t0 > v0 || (t0 == v0 && ti0 < i0)) { v0 = t0; i0 = ti0; }
        double t1 = __shfl_xor(v1, off); int ti1 = __shfl_xor(i1, off);
        if (t1 > v1 || (t1 == v1 && ti1 < i1)) { v1 = t1; i1 = ti1; }
      }
      // wave-local exp sums relative to wave max (S==0 lanes contribute)
      double e0 = (S == 0) ? exp(lgv0 - v0) : 0.0;
      double e1 = (S == 0) ? exp(lgv1 - v1) : 0.0;
      double s20 = e0 * (lgv0 - v0);
      double s21 = e1 * (lgv1 - v1);
#pragma unroll
      for (int off = 1; off < 64; off <<= 1) {
        e0 += __shfl_xor(e0, off);
        s20 += __shfl_xor(s20, off);
        e1 += __shfl_xor(e1, off);
        s21 += __shfl_xor(s21, off);
      }
      if (LN == 0) {
        redA[WV][0] = v0; redI[WV][0] = i0; redB[WV][0] = e0; redC[WV][0] = s20;
        redA[WV][1] = v1; redI[WV][1] = i1; redB[WV][1] = e1; redC[WV][1] = s21;
      }
    }
    __syncthreads();  // B3: per-wave stats ready

    // ---- P4: wave-0 global combine + outputs; all threads prefetch next gi/x --
    if (tid < 32) {
      int r = LN >> 4, w = LN & 15;
      double mw = redA[w][r];
      int iw = redI[w][r];
      double s1w = redB[w][r], s2w = redC[w][r];
      double m = mw;
      int am = iw;
#pragma unroll
      for (int off = 1; off < 16; off <<= 1) {
        double om = __shfl_xor(m, off); int oi = __shfl_xor(am, off);
        if (om > m || (om == m && oi < am)) { m = om; am = oi; }
      }
      double sc = exp(mw - m);  // 0 for fully-masked waves -> kills junk terms
      double S1 = s1w * sc;
      double S2 = (s2w + (mw - m) * s1w) * sc;
#pragma unroll
      for (int off = 1; off < 16; off <<= 1) {
        S1 += __shfl_xor(S1, off);
        S2 += __shfl_xor(S2, off);
      }
      if (w == 0) {
        double lS = log(S1);
        double logZ = m + lS;
        size_t row = (size_t)(b0 + r) * N_;
        out[row + t] = (float)am;
        out[(size_t)B_ * N_ + row + t] = (float)(lg[r][am] - logZ);
        out[2 * (size_t)B_ * N_ + row + t] = (float)(lS - S2 / S1);
        maskS[r][am] = 0;
      }
    }
    if (USE_GI) {
      // per-thread argmax for its ROW, then nt-prefetch next step's gi triple
      double bv = redA[0][ROW];
      int am = redI[0][ROW];
#pragma unroll 4
      for (int w = 1; w < 16; ++w) {
        double wv = redA[w][ROW]; int wi = redI[w][ROW];
        if (wv > bv || (wv == bv && wi < am)) { bv = wv; am = wi; }
      }
      const double* gp = Gi + ((size_t)(b0 + ROW) * 256 + am) * 768;
      giR[0] = ntload8(gp + O);
      giR[1] = ntload8(gp + 256 + O);
      giR[2] = ntload8(gp + 512 + O);
    } else {
      if (tid < 512) {
        int r = tid >> 8, j = tid & 255;
        double bv = redA[0][r];
        int am = redI[0][r];
#pragma unroll 4
        for (int w = 1; w < 16; ++w) {
          double wv = redA[w][r]; int wi = redI[w][r];
          if (wv > bv || (wv == bv && wi < am)) { bv = wv; am = wi; }
        }
        int c4 = j >> 2;
        int vidx = ((am >> 4) * 16 + (c4 & 15)) * 64 + (4 * (am & 15) + (c4 >> 4));
        const float* ePr = r ? (const float*)eP1 : (const float*)eP0;
        xS[r][j + ((j >> 6) << 1)] = (double)ePr[vidx * 4 + (j & 3)];
      }
    }
    __syncthreads();  // B4: mask, outputs, gathers done
    cur ^= 1;
  }
}

extern "C" void kernel_launch(void* const* d_in, const int* in_sizes, int n_in,
                              void* d_out, int out_size, void* d_ws, size_t ws_size,
                              hipStream_t stream) {
  const float* enc = (const float*)d_in[0];
  const float* init_token = (const float*)d_in[1];
  const float* w_ih = (const float*)d_in[2];
  const float* w_hh = (const float*)d_in[3];
  const float* b_ih = (const float*)d_in[4];
  const float* b_hh = (const float*)d_in[5];
  const float* wq = (const float*)d_in[6];
  const float* bq = (const float*)d_in[7];
  const float* wk = (const float*)d_in[8];
  const float* bk = (const float*)d_in[9];  // folded out by softmax shift-invariance
  (void)bk;
  float* out = (float*)d_out;
  char* wsb = (char*)d_ws;

  // ws layout (bytes)
  float* wihP = (float*)(wsb + 0);            //    786,432
  float* whhP = (float*)(wsb + 786432);       //    786,432
  double* WqkP = (double*)(wsb + 1572864);    //    524,288
  double* bqk = (double*)(wsb + 2097152);     //      2,048
  double* gi0 = (double*)(wsb + 2099200);     //      6,144
  float* encP = (float*)(wsb + 2105344);      // 134,217,728  (Tier-B end: 136,323,072)
  float* wihT = (float*)(wsb + 136323072);    //    786,432
  double* Gi = (double*)(wsb + 137109504);    // 805,306,368  (Tier-A end: 942,415,872)
  const bool useGi = ws_size >= 942415872ull;

  hipLaunchKernelGGL(packW_k, dim3(192), dim3(256), 0, stream, w_ih, wihP);
  hipLaunchKernelGGL(packW_k, dim3(192), dim3(256), 0, stream, w_hh, whhP);
  hipLaunchKernelGGL(wqk_k, dim3(256), dim3(256), 0, stream, wk, wq, bq, WqkP, bqk);
  hipLaunchKernelGGL(encp_k, dim3(64, 512), dim3(256), 0, stream, enc, encP);
  hipLaunchKernelGGL(gi0_k, dim3(1), dim3(768), 0, stream, w_ih, b_ih, init_token, gi0);
  if (useGi) {
    hipLaunchKernelGGL(transpose_k, dim3(8, 24), dim3(32, 8), 0, stream, w_ih, wihT, 768, 256);
    hipLaunchKernelGGL(gi_k, dim3(512), dim3(768), 0, stream, enc, wihT, b_ih, Gi);
    hipLaunchKernelGGL(decode_k<true>, dim3(B_ / 2), dim3(1024), 0, stream, enc, init_token,
                       b_ih, b_hh, wihP, whhP, WqkP, bqk, encP, gi0, Gi, out);
  } else {
    hipLaunchKernelGGL(decode_k<false>, dim3(B_ / 2), dim3(1024), 0, stream, enc, init_token,
                       b_ih, b_hh, wihP, whhP, WqkP, bqk, encP, gi0, Gi, out);
  }
}

// Round 8
// 17043.912 us; speedup vs baseline: 1.1184x; 1.0985x over previous
//
#include <hip/hip_runtime.h>

#define B_ 512
#define N_ 256
#define D_ 256
#define NEGINF (-1e30)
#define LN2_ 0.693147180559945309417232121458

// padded LDS index: +2 doubles per 64 -> the two 128-double slice bases land on
// different banks and stay distinct while walking k.
#define PDX(c) ((c) + (((c) >> 6) << 1))

typedef float v4f __attribute__((ext_vector_type(4)));

__device__ __forceinline__ v4f ntload4(const v4f* p) {
  return __builtin_nontemporal_load(p);
}
__device__ __forceinline__ double ntload8(const double* p) {
  return __builtin_nontemporal_load(p);
}

// ---------------- transpose: out[c][r] = in[r][c], in is R x C ----------------
__global__ void transpose_k(const float* __restrict__ in, float* __restrict__ out,
                            int R, int C) {
  __shared__ float tile[32][33];
  int rb = blockIdx.y * 32, cb = blockIdx.x * 32;
  int tx = threadIdx.x, ty = threadIdx.y;  // block (32,8)
  for (int i = ty; i < 32; i += 8) {
    int r = rb + i, c = cb + tx;
    if (r < R && c < C) tile[i][tx] = in[r * C + c];
  }
  __syncthreads();
  for (int i = ty; i < 32; i += 8) {
    int c = cb + i, r = rb + tx;
    if (r < R && c < C) out[c * R + r] = tile[tx][i];
  }
}

// ---- packW for 8-wave geometry: lane l==LN loads its (O,S) slice -------------
// src w[j][c] (768x256). O=j&255, g=j>>8, WV=O>>5, S=c4>>5, k=c4&31,
// l = 2*(O&31)+S.  dst4[((WV*32+k)*3+g)*64 + l]
__global__ __launch_bounds__(256) void packW_k(const float* __restrict__ in,
                                               float* __restrict__ out) {
  int idx = blockIdx.x * 256 + threadIdx.x;  // 49152 v4f
  int j = idx >> 6, c4 = idx & 63;
  int g = j >> 8, o = j & 255;
  int WV = o >> 5, S = c4 >> 5, k = c4 & 31, l = 2 * (o & 31) + S;
  ((v4f*)out)[((WV * 32 + k) * 3 + g) * 64 + l] = ((const v4f*)in)[idx];
}

// ---- Wqk[c][e] = sum_d wk[d][c]*wq[d][e] (fp64) packed for 8-wave geometry ---
// out index O=c, reduction over e. WV=c>>5, l=2*(c&31)+(e>>7), k=(e&127)>>1.
// dst2[(WV*64+k)*64 + l], comp = e&1.  bqk[c] = sum_d wk[d][c]*bq[d].
__global__ __launch_bounds__(256) void wqk_k(const float* __restrict__ wk,
                                             const float* __restrict__ wq,
                                             const float* __restrict__ bq,
                                             double* __restrict__ WqkP,
                                             double* __restrict__ bqk) {
  int c = blockIdx.x, e = threadIdx.x;
  double acc = 0.0;
  for (int dd = 0; dd < 256; ++dd)
    acc += (double)wk[dd * 256 + c] * (double)wq[dd * 256 + e];
  int WV = c >> 5, l = 2 * (c & 31) + (e >> 7), k = (e & 127) >> 1, comp = e & 1;
  WqkP[(size_t)((WV * 64 + k) * 64 + l) * 2 + comp] = acc;
  if (e == 0) {
    double s = 0.0;
    for (int dd = 0; dd < 256; ++dd) s += (double)wk[dd * 256 + c] * (double)bq[dd];
    bqk[c] = s;
  }
}

// ---- encP: per-row packed for 8-wave geometry --------------------------------
// eP4[b][(WV*32+k)*64 + l]; n = WV*32 + (l>>1), c4 = (l&1)*32 + k
__global__ __launch_bounds__(256) void encp_k(const float* __restrict__ enc,
                                              float* __restrict__ encP) {
  int b = blockIdx.y;
  int idx = blockIdx.x * 256 + threadIdx.x;  // 16384 v4f per b
  int l = idx & 63, rest = idx >> 6;
  int k = rest & 31, WV = rest >> 5;
  int n = WV * 32 + (l >> 1), c4 = (l & 1) * 32 + k;
  ((v4f*)encP)[(size_t)b * 16384 + idx] =
      *(const v4f*)(enc + (size_t)b * 65536 + n * 256 + c4 * 4);
}

// ---- Gi[(b*256+n)*768 + j] = b_ih[j] + sum_c w_ih[j][c]*enc[b][n][c]  (fp64) --
__global__ __launch_bounds__(768) void gi_k(const float* __restrict__ enc,
                                            const float* __restrict__ wihT,
                                            const float* __restrict__ b_ih,
                                            double* __restrict__ Gi) {
  int b = blockIdx.x, j = threadIdx.x;
  __shared__ float encS[32][256];
  const float* encB = enc + (size_t)b * 65536;
  double bias = (double)b_ih[j];
  for (int n0 = 0; n0 < 256; n0 += 32) {
    __syncthreads();
    for (int i = j; i < 2048; i += 768)
      ((float4*)encS)[i] = ((const float4*)(encB + n0 * 256))[i];
    __syncthreads();
    double acc[32];
#pragma unroll
    for (int jj = 0; jj < 32; ++jj) acc[jj] = bias;
    for (int c0 = 0; c0 < 256; c0 += 4) {
      double w0 = (double)wihT[(c0 + 0) * 768 + j];
      double w1 = (double)wihT[(c0 + 1) * 768 + j];
      double w2 = (double)wihT[(c0 + 2) * 768 + j];
      double w3 = (double)wihT[(c0 + 3) * 768 + j];
#pragma unroll
      for (int jj = 0; jj < 32; ++jj) {
        const float4 e = *(const float4*)&encS[jj][c0];
        acc[jj] += w0 * (double)e.x + w1 * (double)e.y + w2 * (double)e.z + w3 * (double)e.w;
      }
    }
#pragma unroll
    for (int jj = 0; jj < 32; ++jj)
      Gi[((size_t)b * 256 + n0 + jj) * 768 + j] = acc[jj];
  }
}

// ---- gi0[j] = b_ih[j] + sum_c w_ih[j][c]*init_token[c]  (fp64, one block) ----
__global__ __launch_bounds__(768) void gi0_k(const float* __restrict__ w_ih,
                                             const float* __restrict__ b_ih,
                                             const float* __restrict__ init_token,
                                             double* __restrict__ gi0) {
  int j = threadIdx.x;
  __shared__ float xs[256];
  if (j < 256) xs[j] = init_token[j];
  __syncthreads();
  double acc = (double)b_ih[j];
  for (int c = 0; c < 256; ++c) acc += (double)w_ih[j * 256 + c] * (double)xs[c];
  gi0[j] = acc;
}

// ---------------- persistent decode: 1 row/block, 512 blocks x 512 thr --------
// 2 independent blocks per CU -> cross-block latency hiding (no lockstep).
template <bool USE_GI>
__global__ __launch_bounds__(512, 4) void decode_k(
    const float* __restrict__ enc, const float* __restrict__ init_token,
    const float* __restrict__ b_ih, const float* __restrict__ b_hh,
    const float* __restrict__ wihP, const float* __restrict__ whhP,
    const double* __restrict__ WqkP, const double* __restrict__ bqk,
    const float* __restrict__ encP, const double* __restrict__ gi0,
    const double* __restrict__ Gi, float* __restrict__ out) {
  const int tid = threadIdx.x;
  const int WV = tid >> 6;            // wave 0..7
  const int LN = tid & 63;            // lane; pack layouts built so l == LN
  const int O = WV * 32 + (LN >> 1);  // output index 0..255
  const int S = LN & 1;               // slice 0/1 (c-range [128S, 128S+128))
  const int b = blockIdx.x;
  const int OP = PDX(O);
  const int CB = S * 132;             // padded base of slice S

  __shared__ alignas(16) double hS[2][264];  // [pingpong][pad(d)]
  __shared__ alignas(16) double xS[264];     // Tier-B only
  __shared__ alignas(16) double qs[264];
  __shared__ unsigned char maskS[N_];
  __shared__ double redA[8], redB[8], redC[8];
  __shared__ int redI[8];

  const float* encB = enc + (size_t)b * 65536;
  const v4f* eP = (const v4f*)encP + (size_t)b * 16384;
  const v4f* wh4 = (const v4f*)whhP;
  const v4f* wi4 = (const v4f*)wihP;
  const double2* Wp2 = (const double2*)WqkP;

  double giR[3];  // Tier-A: this thread's (r,z,n) input-gate values for O

  // ---------------- init ----------------
  if (tid < 256) {
    maskS[tid] = 1;
    if (!USE_GI) xS[PDX(tid)] = (double)init_token[tid];
  }
  if (USE_GI) {
#pragma unroll
    for (int g = 0; g < 3; ++g) giR[g] = gi0[g * 256 + O];
  }
  {
    double p = 0.0;
    const float* e0 = encB + (size_t)(S * 128) * 256 + O;
#pragma unroll 4
    for (int n = 0; n < 128; ++n) p += (double)e0[n * 256];
    p += __shfl_xor(p, 1);
    if (S == 0) hS[0][OP] = p * (1.0 / 256.0);
  }
  __syncthreads();

  int cur = 0;
  for (int t = 0; t < N_; ++t) {
    const int nxt = cur ^ 1;
    // ---- P1: GRU h-side (+ x-side if Tier-B) ----
    double ghr = 0, ghz = 0, ghn = 0;
    double air = 0, aiz = 0, ain = 0;
#pragma unroll 4
    for (int k = 0; k < 32; ++k) {
      int wb = ((WV * 32 + k) * 3) * 64 + LN;
      v4f br = wh4[wb], bz = wh4[wb + 64], bn = wh4[wb + 128];
      const double* h = &hS[cur][CB + 4 * k + ((k >> 4) << 1)];
#pragma unroll
      for (int i = 0; i < 4; ++i) {
        ghr += (double)br[i] * h[i];
        ghz += (double)bz[i] * h[i];
        ghn += (double)bn[i] * h[i];
      }
      if (!USE_GI) {
        v4f ar = wi4[wb], az = wi4[wb + 64], an = wi4[wb + 128];
        const double* x = &xS[CB + 4 * k + ((k >> 4) << 1)];
#pragma unroll
        for (int i = 0; i < 4; ++i) {
          air += (double)ar[i] * x[i];
          aiz += (double)az[i] * x[i];
          ain += (double)an[i] * x[i];
        }
      }
    }
    ghr += __shfl_xor(ghr, 1);
    ghz += __shfl_xor(ghz, 1);
    ghn += __shfl_xor(ghn, 1);
    if (!USE_GI) {
      air += __shfl_xor(air, 1);
      aiz += __shfl_xor(aiz, 1);
      ain += __shfl_xor(ain, 1);
    }
    {
      double gir, giz, gin;
      if (USE_GI) {
        gir = giR[0]; giz = giR[1]; gin = giR[2];  // bias folded in
      } else {
        gir = air + (double)b_ih[O];
        giz = aiz + (double)b_ih[256 + O];
        gin = ain + (double)b_ih[512 + O];
      }
      double hr_ = ghr + (double)b_hh[O];
      double hz_ = ghz + (double)b_hh[256 + O];
      double hn_ = ghn + (double)b_hh[512 + O];
      double rr = 1.0 / (1.0 + exp(-(gir + hr_)));
      double zz = 1.0 / (1.0 + exp(-(giz + hz_)));
      double nn = tanh(gin + rr * hn_);
      double hold = hS[cur][OP];
      double hnew = (1.0 - zz) * nn + zz * hold;
      if (S == 0) hS[nxt][OP] = hnew;
    }
    __syncthreads();  // B1: h ready

    // ---- P2: qk = Wqk·h + bqk ----
    {
      double q = 0;
#pragma unroll 8
      for (int k = 0; k < 64; ++k) {
        double2 wv = Wp2[(WV * 64 + k) * 64 + LN];
        const double* h = &hS[nxt][CB + 2 * k + ((k >> 5) << 1)];
        q += wv.x * h[0] + wv.y * h[1];
      }
      q += __shfl_xor(q, 1);
      if (S == 0) qs[OP] = q + bqk[O];
    }
    __syncthreads();  // B2: qs ready

    // ---- P3: logits + wave argmax + wave-local exp sums ----
    {
      double p = 0;
#pragma unroll 8
      for (int k = 0; k < 32; ++k) {
        v4f e = ntload4(eP + (WV * 32 + k) * 64 + LN);
        const double* qa = &qs[CB + 4 * k + ((k >> 4) << 1)];
#pragma unroll
        for (int i = 0; i < 4; ++i) p += (double)e[i] * qa[i];
      }
      p += __shfl_xor(p, 1);
      double lgv = 0.0625 * p;
      if (!maskS[O]) lgv = NEGINF;
      double v = lgv;
      int idx = O;
#pragma unroll
      for (int off = 1; off < 64; off <<= 1) {
        double ov = __shfl_xor(v, off); int oi = __shfl_xor(idx, off);
        if (ov > v || (ov == v && oi < idx)) { v = ov; idx = oi; }
      }
      // both S-lanes contribute the same term -> sums are 2x (corrected by LN2_)
      double e1 = exp(lgv - v);
      double s2 = e1 * (lgv - v);
#pragma unroll
      for (int off = 1; off < 64; off <<= 1) {
        e1 += __shfl_xor(e1, off);
        s2 += __shfl_xor(s2, off);
      }
      if (LN == 0) { redA[WV] = v; redI[WV] = idx; redB[WV] = e1; redC[WV] = s2; }
    }
    __syncthreads();  // B3: per-wave stats ready

    // ---- P4: 8-lane global combine + outputs; all threads prefetch next gi/x --
    if (tid < 8) {
      double mw = redA[tid];
      int iw = redI[tid];
      double s1w = redB[tid], s2w = redC[tid];
      double m = mw;
      int am = iw;
#pragma unroll
      for (int off = 1; off < 8; off <<= 1) {
        double om = __shfl_xor(m, off); int oi = __shfl_xor(am, off);
        if (om > m || (om == m && oi < am)) { m = om; am = oi; }
      }
      double sc = exp(mw - m);  // 0 for fully-masked waves -> kills junk terms
      double S1 = s1w * sc;
      double S2 = (s2w + (mw - m) * s1w) * sc;
#pragma unroll
      for (int off = 1; off < 8; off <<= 1) {
        S1 += __shfl_xor(S1, off);
        S2 += __shfl_xor(S2, off);
      }
      if (tid == 0) {
        double lS = log(S1) - LN2_;  // remove the 2x duplication
        size_t row = (size_t)b * N_;
        out[row + t] = (float)am;                         // tours
        out[(size_t)B_ * N_ + row + t] = (float)(-lS);    // logp of argmax = m - logZ
        out[2 * (size_t)B_ * N_ + row + t] = (float)(lS - S2 / S1);  // entropy
        maskS[am] = 0;
      }
    }
    {
      // per-thread argmax scan (8 entries), then prefetch next x-transform
      double bv = redA[0];
      int am = redI[0];
#pragma unroll
      for (int w = 1; w < 8; ++w) {
        double wv = redA[w]; int wi = redI[w];
        if (wv > bv || (wv == bv && wi < am)) { bv = wv; am = wi; }
      }
      if (USE_GI) {
        const double* gp = Gi + ((size_t)b * 256 + am) * 768;
        giR[0] = ntload8(gp + O);
        giR[1] = ntload8(gp + 256 + O);
        giR[2] = ntload8(gp + 512 + O);
      } else {
        if (tid < 256) {
          int j = tid, c4 = j >> 2;
          int vidx = ((am >> 5) * 32 + (c4 & 31)) * 64 + (2 * (am & 31) + (c4 >> 5));
          xS[PDX(j)] = (double)((const float*)eP)[vidx * 4 + (j & 3)];
        }
      }
    }
    __syncthreads();  // B4: mask, outputs, prefetch done
    cur ^= 1;
  }
}

extern "C" void kernel_launch(void* const* d_in, const int* in_sizes, int n_in,
                              void* d_out, int out_size, void* d_ws, size_t ws_size,
                              hipStream_t stream) {
  const float* enc = (const float*)d_in[0];
  const float* init_token = (const float*)d_in[1];
  const float* w_ih = (const float*)d_in[2];
  const float* w_hh = (const float*)d_in[3];
  const float* b_ih = (const float*)d_in[4];
  const float* b_hh = (const float*)d_in[5];
  const float* wq = (const float*)d_in[6];
  const float* bq = (const float*)d_in[7];
  const float* wk = (const float*)d_in[8];
  const float* bk = (const float*)d_in[9];  // folded out by softmax shift-invariance
  (void)bk;
  float* out = (float*)d_out;
  char* wsb = (char*)d_ws;

  // ws layout (bytes)
  float* wihP = (float*)(wsb + 0);            //    786,432
  float* whhP = (float*)(wsb + 786432);       //    786,432
  double* WqkP = (double*)(wsb + 1572864);    //    524,288
  double* bqk = (double*)(wsb + 2097152);     //      2,048
  double* gi0 = (double*)(wsb + 2099200);     //      6,144
  float* encP = (float*)(wsb + 2105344);      // 134,217,728  (Tier-B end: 136,323,072)
  float* wihT = (float*)(wsb + 136323072);    //    786,432
  double* Gi = (double*)(wsb + 137109504);    // 805,306,368  (Tier-A end: 942,415,872)
  const bool useGi = ws_size >= 942415872ull;

  hipLaunchKernelGGL(packW_k, dim3(192), dim3(256), 0, stream, w_ih, wihP);
  hipLaunchKernelGGL(packW_k, dim3(192), dim3(256), 0, stream, w_hh, whhP);
  hipLaunchKernelGGL(wqk_k, dim3(256), dim3(256), 0, stream, wk, wq, bq, WqkP, bqk);
  hipLaunchKernelGGL(encp_k, dim3(64, 512), dim3(256), 0, stream, enc, encP);
  hipLaunchKernelGGL(gi0_k, dim3(1), dim3(768), 0, stream, w_ih, b_ih, init_token, gi0);
  if (useGi) {
    hipLaunchKernelGGL(transpose_k, dim3(8, 24), dim3(32, 8), 0, stream, w_ih, wihT, 768, 256);
    hipLaunchKernelGGL(gi_k, dim3(512), dim3(768), 0, stream, enc, wihT, b_ih, Gi);
    hipLaunchKernelGGL(decode_k<true>, dim3(B_), dim3(512), 0, stream, enc, init_token,
                       b_ih, b_hh, wihP, whhP, WqkP, bqk, encP, gi0, Gi, out);
  } else {
    hipLaunchKernelGGL(decode_k<false>, dim3(B_), dim3(512), 0, stream, enc, init_token,
                       b_ih, b_hh, wihP, whhP, WqkP, bqk, encP, gi0, Gi, out);
  }
}